// Round 5
// baseline (193.740 us; speedup 1.0000x reference)
//
#include <hip/hip_runtime.h>
#include <stdint.h>

#define T_SEQ 2048
#define NH 16
#define HD 64
#define M_DIM 4096      // B*T
#define K_DIM 1024      // C

typedef __attribute__((ext_vector_type(8))) short bf16x8;
typedef __attribute__((ext_vector_type(4))) short bf16x4;
typedef __attribute__((ext_vector_type(4))) float f32x4;
typedef __attribute__((ext_vector_type(4))) unsigned short u16x4;

__device__ __forceinline__ unsigned short f2bf(float f) {
  union { float f; uint32_t u; } x; x.f = f;
  uint32_t u = x.u;
  return (unsigned short)((u + 0x7fffu + ((u >> 16) & 1u)) >> 16);
}

__device__ __forceinline__ uint32_t cvtpk_bf16(float a, float b) {
  uint32_t r;
  asm("v_cvt_pk_bf16_f32 %0, %1, %2" : "=v"(r) : "v"(a), "v"(b));
  return r;
}

// 16x16x16 bf16 MFMA via inline asm (A k-span = lg*4+j matches S-reg layout).
// D/C tied ("+v") -> back-to-back accumulate, no C/D copy.
__device__ __forceinline__ f32x4 mfma16(bf16x4 a, bf16x4 b, f32x4 c) {
  asm("v_mfma_f32_16x16x16_bf16 %0, %1, %2, %0" : "+v"(c) : "v"(a), "v"(b));
  return c;
}

#define GLOAD16(g, l) __builtin_amdgcn_global_load_lds( \
    (const __attribute__((address_space(1))) unsigned int*)(g), \
    (__attribute__((address_space(3))) unsigned int*)(l), 16, 0, 0)

// ---- fused preprocessing: x->bf16, w_attn->bf16^T, w_proj->bf16^T ----
__device__ __forceinline__ void do_convert(const float* __restrict__ src,
                                           unsigned short* __restrict__ dst, int bid) {
  int idx = (bid * 256 + threadIdx.x) * 4;
  f32x4 v = *(const f32x4*)(src + idx);
  u16x4 o;
  #pragma unroll
  for (int i = 0; i < 4; ++i) o[i] = f2bf(v[i]);
  *(u16x4*)(dst + idx) = o;
}

__device__ __forceinline__ void do_transpose(const float* __restrict__ src,
                                             unsigned short* __restrict__ dst,
                                             int R, int Cn, int bx, int by,
                                             float (*tile)[65]) {
  const int r0 = by * 64, c0 = bx * 64;
  const int t = threadIdx.x;
  const int rr = t >> 4;
  const int c4 = (t & 15) * 4;
  #pragma unroll
  for (int p = 0; p < 4; ++p) {
    f32x4 v = *(const f32x4*)(src + (size_t)(r0 + p * 16 + rr) * Cn + c0 + c4);
    #pragma unroll
    for (int i = 0; i < 4; ++i) tile[p * 16 + rr][c4 + i] = v[i];
  }
  __syncthreads();
  #pragma unroll
  for (int p = 0; p < 4; ++p) {
    const int cl = p * 16 + rr;
    u16x4 o;
    #pragma unroll
    for (int i = 0; i < 4; ++i) o[i] = f2bf(tile[c4 + i][cl]);
    *(u16x4*)(dst + (size_t)(c0 + cl) * R + r0 + c4) = o;
  }
}

__global__ __launch_bounds__(256) void prep_kernel(
    const float* __restrict__ x, unsigned short* __restrict__ xb,
    const float* __restrict__ w_attn, unsigned short* __restrict__ wqkvT,
    const float* __restrict__ w_proj, unsigned short* __restrict__ wprojT) {
  __shared__ float tile[64][65];
  const int b = blockIdx.x;
  if (b < 4096) {
    do_convert(x, xb, b);
  } else if (b < 4096 + 768) {
    const int bid = b - 4096;
    do_transpose(w_attn, wqkvT, 1024, 3072, bid % 48, bid / 48, tile);
  } else {
    const int bid = b - 4864;
    do_transpose(w_proj, wprojT, 1024, 1024, bid % 16, bid / 16, tile);
  }
}

// ---- 2-phase double-buffered GEMM: C[M][N] = A[M][K]*Bt[N][K]^T + bias ----
template <int MODE, int WM>
__global__ __launch_bounds__(WM * 128) void gemm2_kernel(
    const unsigned short* __restrict__ A,
    const unsigned short* __restrict__ Bt,
    const float* __restrict__ bias,
    unsigned short* __restrict__ qout,
    unsigned short* __restrict__ kout,
    unsigned short* __restrict__ vTout,
    float* __restrict__ fout) {
  constexpr int BM = WM * 64;
  constexpr int NT = WM * 128;
  constexpr int U_A = BM * 4;
  constexpr int NU = (U_A + 512) / NT;
  __shared__ __align__(16) unsigned short As[2][BM * 32];
  __shared__ __align__(16) unsigned short Bs[2][128 * 32];
  const int t = threadIdx.x;
  const int w = t >> 6, l = t & 63;
  const int wr = w >> 1, wc = w & 1;
  const int lr = l & 15, lg = l >> 4;
  const int br = blockIdx.y, bc = blockIdx.x;

  f32x4 acc[4][4];
  const f32x4 zf = {0.f, 0.f, 0.f, 0.f};
  #pragma unroll
  for (int i = 0; i < 4; ++i)
    #pragma unroll
    for (int j = 0; j < 4; ++j) acc[i][j] = zf;

  const unsigned short* Abase = A + (size_t)(br * BM) * K_DIM;
  const unsigned short* Bbase = Bt + (size_t)(bc * 128) * K_DIM;

  #define STAGE(k0, buf) do {                                                    \
    _Pragma("unroll")                                                            \
    for (int i = 0; i < NU; ++i) {                                               \
      const int u = i * NT + t;                                                  \
      if (u < U_A) {                                                             \
        GLOAD16(Abase + (size_t)(u >> 2) * K_DIM + (k0) + (u & 3) * 8,           \
                &As[buf][u * 8]);                                                \
      } else {                                                                   \
        const int v = u - U_A;                                                   \
        GLOAD16(Bbase + (size_t)(v >> 2) * K_DIM + (k0) + (v & 3) * 8,           \
                &Bs[buf][v * 8]);                                                \
      }                                                                          \
    }                                                                            \
  } while (0)

  #define COMPUTE(buf) do {                                                      \
    bf16x8 af[4], bfv[4];                                                        \
    _Pragma("unroll")                                                            \
    for (int f = 0; f < 4; ++f) {                                                \
      af[f]  = *(const bf16x8*)(&As[buf][(wr * 64 + f * 16 + lr) * 32 + lg * 8]);\
      bfv[f] = *(const bf16x8*)(&Bs[buf][(wc * 64 + f * 16 + lr) * 32 + lg * 8]);\
    }                                                                            \
    _Pragma("unroll")                                                            \
    for (int fr = 0; fr < 4; ++fr)                                               \
      _Pragma("unroll")                                                          \
      for (int fc = 0; fc < 4; ++fc)                                             \
        acc[fr][fc] = __builtin_amdgcn_mfma_f32_16x16x32_bf16(af[fr], bfv[fc],   \
                                                              acc[fr][fc], 0, 0, 0); \
  } while (0)

  STAGE(0, 0);
  __syncthreads();
  #pragma unroll 1
  for (int k0 = 0; k0 < K_DIM; k0 += 64) {
    if (k0 + 32 < K_DIM) STAGE(k0 + 32, 1);
    COMPUTE(0);
    __syncthreads();
    if (k0 + 64 < K_DIM) STAGE(k0 + 64, 0);
    COMPUTE(1);
    __syncthreads();
  }
  #undef STAGE
  #undef COMPUTE

  #pragma unroll
  for (int fr = 0; fr < 4; ++fr) {
    #pragma unroll
    for (int fc = 0; fc < 4; ++fc) {
      const int m0 = br * BM + wr * 64 + fr * 16 + lg * 4;
      const int n  = bc * 128 + wc * 64 + fc * 16 + lr;
      if (MODE == 0) {
        const int which = n >> 10, rem = n & 1023;
        const int h = rem >> 6, d = rem & 63;
        const int b = m0 >> 11, tt0 = m0 & 2047;
        const int bh = b * NH + h;
        if (which == 2) {
          u16x4 pack;
          #pragma unroll
          for (int r = 0; r < 4; ++r) pack[r] = f2bf(acc[fr][fc][r] + bias[n]);
          *(u16x4*)(vTout + ((size_t)bh * HD + d) * T_SEQ + tt0) = pack;
        } else {
          unsigned short* o = (which == 0) ? qout : kout;
          const float sc = (which == 0) ? 0.18033688011112042f : 1.0f;  // 0.125*log2(e)
          #pragma unroll
          for (int r = 0; r < 4; ++r)
            o[((size_t)bh * T_SEQ + tt0 + r) * HD + d] = f2bf((acc[fr][fc][r] + bias[n]) * sc);
        }
      } else {
        #pragma unroll
        for (int r = 0; r < 4; ++r)
          fout[(size_t)(m0 + r) * 1024 + n] = acc[fr][fc][r] + bias[n];
      }
    }
  }
}

// ---- causal flash attention, v4 ----
// 1024 blocks = (bh, qt), qt-descending (LPT balance), bh XCD-grouped.
// 4 waves x 16 q-rows. K/V dbuf LDS (32KB), no P array: PV uses
// v_mfma_f32_16x16x16_bf16 whose A-frag layout == S register layout.
__global__ __launch_bounds__(256, 4) void flash_attn_kernel(
    const unsigned short* __restrict__ qg,
    const unsigned short* __restrict__ kg,
    const unsigned short* __restrict__ vTg,
    unsigned short* __restrict__ yg) {
  __shared__ __align__(16) unsigned short Ks[2][64 * 64];
  __shared__ __align__(16) unsigned short Vs[2][64 * 64];

  const int t = threadIdx.x;
  const int w = t >> 6, l = t & 63;
  const int lr = l & 15, lg = l >> 4;
  const int i = blockIdx.x;
  const int bh = (i & 7) * 4 + ((i >> 3) & 3);   // 4 heads per XCD
  const int qt = 31 - (i >> 5);                  // longest blocks launch first
  const int nt = qt + 1;
  const int qw = qt * 64 + w * 16;
  const int qrow = qw + lr;
  const int swz = lr & 7;

  const int srow0 = t >> 3;
  const int sch = t & 7;

  const size_t kgb = (size_t)bh * T_SEQ * HD;
  const size_t vgb = (size_t)bh * HD * T_SEQ;
  const f32x4 zf = {0.f, 0.f, 0.f, 0.f};

  const size_t qoff = ((size_t)bh * T_SEQ + qw + lr) * HD + lg * 8;
  const bf16x8 qf0 = *(const bf16x8*)(qg + qoff);      // pre-scaled by 0.125*log2e
  const bf16x8 qf1 = *(const bf16x8*)(qg + qoff + 32);

  f32x4 acc[4];
  #pragma unroll
  for (int k = 0; k < 4; ++k) acc[k] = zf;
  float m_run = 0.f;
  float l_part = 0.f;

  #pragma unroll
  for (int sh = 0; sh < 2; ++sh) {
    const int row = sh * 32 + srow0;
    const int sc = (sch ^ (row & 7)) * 8;
    GLOAD16(kg + kgb + (size_t)row * HD + sc, Ks[0] + row * 64 + sch * 8);
    GLOAD16(vTg + vgb + (size_t)row * T_SEQ + sc, Vs[0] + row * 64 + sch * 8);
  }
  __syncthreads();

  int cur = 0;
  #pragma unroll 1
  for (int it = 0; it < nt; ++it) {
    const int kv0 = it * 64;
    if (it + 1 < nt) {
      const int kvn = kv0 + 64;
      #pragma unroll
      for (int sh = 0; sh < 2; ++sh) {
        const int row = sh * 32 + srow0;
        const int sc = (sch ^ (row & 7)) * 8;
        GLOAD16(kg + kgb + (size_t)(kvn + row) * HD + sc, Ks[cur ^ 1] + row * 64 + sch * 8);
        GLOAD16(vTg + vgb + (size_t)row * T_SEQ + kvn + sc, Vs[cur ^ 1] + row * 64 + sch * 8);
      }
    }

    // QK^T (swapped): lane holds (q=lr, tkv = kv0 + fc*16 + lg*4 + r)
    f32x4 s[4];
    __builtin_amdgcn_s_setprio(1);
    #pragma unroll
    for (int fc = 0; fc < 4; ++fc) {
      const unsigned short* kr = Ks[cur] + (fc * 16 + lr) * 64;
      const bf16x8 k0v = *(const bf16x8*)(kr + ((lg ^ swz) * 8));
      const bf16x8 k1v = *(const bf16x8*)(kr + (((lg + 4) ^ swz) * 8));
      f32x4 sv = zf;
      sv = __builtin_amdgcn_mfma_f32_16x16x32_bf16(k0v, qf0, sv, 0, 0, 0);
      sv = __builtin_amdgcn_mfma_f32_16x16x32_bf16(k1v, qf1, sv, 0, 0, 0);
      s[fc] = sv;
    }
    __builtin_amdgcn_s_setprio(0);

    if (it == nt - 1) {           // causal mask: diagonal tile only
      #pragma unroll
      for (int fc = 0; fc < 4; ++fc)
        #pragma unroll
        for (int r = 0; r < 4; ++r) {
          const int tkv = kv0 + fc * 16 + lg * 4 + r;
          if (tkv > qrow) s[fc][r] = -1e30f;
        }
    }

    float mt = s[0][0];
    #pragma unroll
    for (int fc = 0; fc < 4; ++fc)
      #pragma unroll
      for (int r = 0; r < 4; ++r) mt = fmaxf(mt, s[fc][r]);
    if (__any(mt > m_run + 8.f)) {       // defer-max: rare path
      float mrow = fmaxf(mt, __shfl_xor(mt, 16));
      mrow = fmaxf(mrow, __shfl_xor(mrow, 32));
      const float m_new = fmaxf(m_run, mrow);
      const float fac = __builtin_amdgcn_exp2f(m_run - m_new);
      l_part *= fac;
      float frs[4];
      #pragma unroll
      for (int r = 0; r < 4; ++r) frs[r] = __shfl(fac, lg * 4 + r);
      #pragma unroll
      for (int fd = 0; fd < 4; ++fd)
        #pragma unroll
        for (int r = 0; r < 4; ++r) acc[fd][r] *= frs[r];
      m_run = m_new;
    }

    // P = exp2(s - m) packed to bf16 pairs; stays in registers
    union { uint32_t d[2]; bf16x4 v; } pkd[4];
    #pragma unroll
    for (int fc = 0; fc < 4; ++fc) {
      float e0 = __builtin_amdgcn_exp2f(s[fc][0] - m_run);
      float e1 = __builtin_amdgcn_exp2f(s[fc][1] - m_run);
      float e2 = __builtin_amdgcn_exp2f(s[fc][2] - m_run);
      float e3 = __builtin_amdgcn_exp2f(s[fc][3] - m_run);
      l_part += (e0 + e1) + (e2 + e3);
      pkd[fc].d[0] = cvtpk_bf16(e0, e1);
      pkd[fc].d[1] = cvtpk_bf16(e2, e3);
    }

    // PV: 16x16x16 MFMA, A = pkd[fc] (reg-resident), B = V-frag 8B reads
    __builtin_amdgcn_s_setprio(1);
    #pragma unroll
    for (int fd = 0; fd < 4; ++fd) {
      const unsigned short* vr = Vs[cur] + (fd * 16 + lr) * 64;
      bf16x4 vf[4];
      #pragma unroll
      for (int fc = 0; fc < 4; ++fc) {
        const int ch = (fc * 2 + (lg >> 1)) ^ swz;
        vf[fc] = *(const bf16x4*)(vr + ch * 8 + (lg & 1) * 4);
      }
      f32x4 a = acc[fd];
      #pragma unroll
      for (int fc = 0; fc < 4; ++fc) a = mfma16(pkd[fc].v, vf[fc], a);
      acc[fd] = a;
    }
    __builtin_amdgcn_s_setprio(0);
    __syncthreads();
    cur ^= 1;
  }

  float lsum = l_part;
  lsum += __shfl_xor(lsum, 16);
  lsum += __shfl_xor(lsum, 32);

  const int b = bh >> 4, h = bh & 15;
  #pragma unroll
  for (int r = 0; r < 4; ++r) {
    const float lv = __shfl(lsum, lg * 4 + r);
    const float linv = 1.f / lv;
    const int tt = qw + lg * 4 + r;
    #pragma unroll
    for (int fd = 0; fd < 4; ++fd) {
      const int d = fd * 16 + lr;
      yg[(((size_t)b * T_SEQ + tt) * NH + h) * HD + d] = f2bf(acc[fd][r] * linv);
    }
  }
}

extern "C" void kernel_launch(void* const* d_in, const int* in_sizes, int n_in,
                              void* d_out, int out_size, void* d_ws, size_t ws_size,
                              hipStream_t stream) {
  (void)in_sizes; (void)n_in; (void)out_size; (void)ws_size;
  const float* x      = (const float*)d_in[0];
  const float* w_attn = (const float*)d_in[1];
  const float* b_attn = (const float*)d_in[2];
  const float* w_proj = (const float*)d_in[3];
  const float* b_proj = (const float*)d_in[4];
  float* out = (float*)d_out;

  char* ws = (char*)d_ws;
  unsigned short* xb     = (unsigned short*)(ws);                  // 8 MiB  [4096][1024]
  unsigned short* wqkvT  = (unsigned short*)(ws + (8ull  << 20));  // 6 MiB  [3072][1024]
  unsigned short* wprojT = (unsigned short*)(ws + (14ull << 20));  // 2 MiB  [1024][1024]
  unsigned short* qb     = (unsigned short*)(ws + (16ull << 20));  // 8 MiB  [BH][T][D]
  unsigned short* kb     = (unsigned short*)(ws + (24ull << 20));  // 8 MiB  [BH][T][D]
  unsigned short* vT     = (unsigned short*)(ws + (32ull << 20));  // 8 MiB  [BH][D][T]
  unsigned short* yb     = (unsigned short*)(ws + (40ull << 20));  // 8 MiB  [4096][1024]

  prep_kernel<<<5120, 256, 0, stream>>>(x, xb, w_attn, wqkvT, w_proj, wprojT);
  gemm2_kernel<0, 2><<<dim3(24, 32), 256, 0, stream>>>(xb, wqkvT, b_attn, qb, kb, vT, nullptr);
  flash_attn_kernel<<<1024, 256, 0, stream>>>(qb, kb, vT, yb);
  gemm2_kernel<1, 2><<<dim3(8, 32), 256, 0, stream>>>(yb, wprojT, b_proj, nullptr, nullptr, nullptr, out);
}

// Round 6
// 179.933 us; speedup vs baseline: 1.0767x; 1.0767x over previous
//
#include <hip/hip_runtime.h>
#include <stdint.h>

#define T_SEQ 2048
#define NH 16
#define HD 64
#define M_DIM 4096      // B*T
#define K_DIM 1024      // C

typedef __attribute__((ext_vector_type(8))) short bf16x8;
typedef __attribute__((ext_vector_type(4))) short bf16x4;
typedef __attribute__((ext_vector_type(4))) float f32x4;
typedef __attribute__((ext_vector_type(4))) unsigned short u16x4;

__device__ __forceinline__ unsigned short f2bf(float f) {
  union { float f; uint32_t u; } x; x.f = f;
  uint32_t u = x.u;
  return (unsigned short)((u + 0x7fffu + ((u >> 16) & 1u)) >> 16);
}

__device__ __forceinline__ uint32_t cvtpk_bf16(float a, float b) {
  uint32_t r;
  asm("v_cvt_pk_bf16_f32 %0, %1, %2" : "=v"(r) : "v"(a), "v"(b));
  return r;
}

// 16x16x16 bf16 MFMA (A k-span = lg*4+j matches S-reg layout); D/C tied.
__device__ __forceinline__ f32x4 mfma16(bf16x4 a, bf16x4 b, f32x4 c) {
  asm("v_mfma_f32_16x16x16_bf16 %0, %1, %2, %0" : "+v"(c) : "v"(a), "v"(b));
  return c;
}

#define GLOAD16(g, l) __builtin_amdgcn_global_load_lds( \
    (const __attribute__((address_space(1))) unsigned int*)(g), \
    (__attribute__((address_space(3))) unsigned int*)(l), 16, 0, 0)

// ---- fused preprocessing: x->bf16, w_attn->bf16^T, w_proj->bf16^T ----
__device__ __forceinline__ void do_convert(const float* __restrict__ src,
                                           unsigned short* __restrict__ dst, int bid) {
  int idx = (bid * 256 + threadIdx.x) * 4;
  f32x4 v = *(const f32x4*)(src + idx);
  u16x4 o;
  #pragma unroll
  for (int i = 0; i < 4; ++i) o[i] = f2bf(v[i]);
  *(u16x4*)(dst + idx) = o;
}

__device__ __forceinline__ void do_transpose(const float* __restrict__ src,
                                             unsigned short* __restrict__ dst,
                                             int R, int Cn, int bx, int by,
                                             float (*tile)[65]) {
  const int r0 = by * 64, c0 = bx * 64;
  const int t = threadIdx.x;
  const int rr = t >> 4;
  const int c4 = (t & 15) * 4;
  #pragma unroll
  for (int p = 0; p < 4; ++p) {
    f32x4 v = *(const f32x4*)(src + (size_t)(r0 + p * 16 + rr) * Cn + c0 + c4);
    #pragma unroll
    for (int i = 0; i < 4; ++i) tile[p * 16 + rr][c4 + i] = v[i];
  }
  __syncthreads();
  #pragma unroll
  for (int p = 0; p < 4; ++p) {
    const int cl = p * 16 + rr;
    u16x4 o;
    #pragma unroll
    for (int i = 0; i < 4; ++i) o[i] = f2bf(tile[c4 + i][cl]);
    *(u16x4*)(dst + (size_t)(c0 + cl) * R + r0 + c4) = o;
  }
}

__global__ __launch_bounds__(256) void prep_kernel(
    const float* __restrict__ x, unsigned short* __restrict__ xb,
    const float* __restrict__ w_attn, unsigned short* __restrict__ wqkvT,
    const float* __restrict__ w_proj, unsigned short* __restrict__ wprojT) {
  __shared__ float tile[64][65];
  const int b = blockIdx.x;
  if (b < 4096) {
    do_convert(x, xb, b);
  } else if (b < 4096 + 768) {
    const int bid = b - 4096;
    do_transpose(w_attn, wqkvT, 1024, 3072, bid % 48, bid / 48, tile);
  } else {
    const int bid = b - 4864;
    do_transpose(w_proj, wprojT, 1024, 1024, bid % 16, bid / 16, tile);
  }
}

// ---- 3-stage pipelined GEMM (depth-2 prefetch, counted vmcnt, raw barrier) ----
// C[M][N] = A[M][K]*Bt[N][K]^T + bias. 128x128 tile, BK=32, 4 waves.
// Per K-step: wait vmcnt(4) [stage ks landed, ks+1 in flight] -> barrier ->
// issue stage ks+2 -> ds_read+MFMA. Loads span a full K-step + compute.
template <int MODE>
__global__ __launch_bounds__(256, 3) void gemm3_kernel(
    const unsigned short* __restrict__ A,
    const unsigned short* __restrict__ Bt,
    const float* __restrict__ bias,
    unsigned short* __restrict__ qout,
    unsigned short* __restrict__ kout,
    unsigned short* __restrict__ vTout,
    float* __restrict__ fout) {
  constexpr int NS = K_DIM / 32;                 // 32 K-stages
  constexpr int NWG = (MODE == 0) ? 768 : 256;
  constexpr int NBC = (MODE == 0) ? 24 : 8;
  __shared__ __align__(16) unsigned short As[3][128 * 32];
  __shared__ __align__(16) unsigned short Bs[3][128 * 32];
  const int t = threadIdx.x;
  const int w = t >> 6, l = t & 63;
  const int wr = w >> 1, wc = w & 1;
  const int lr = l & 15, lg = l >> 4;
  // bijective XCD swizzle (NWG % 8 == 0): each XCD gets a contiguous chunk
  const int wg = (blockIdx.x & 7) * (NWG >> 3) + (blockIdx.x >> 3);
  const int bc = wg % NBC, br = wg / NBC;

  f32x4 acc[4][4];
  const f32x4 zf = {0.f, 0.f, 0.f, 0.f};
  #pragma unroll
  for (int i = 0; i < 4; ++i)
    #pragma unroll
    for (int j = 0; j < 4; ++j) acc[i][j] = zf;

  const unsigned short* Abase = A + (size_t)(br * 128) * K_DIM;
  const unsigned short* Bbase = Bt + (size_t)(bc * 128) * K_DIM;
  // per-thread staging: 4 units of 16B (2 for A, 2 for B); unit u covers
  // row u>>2, 16B-chunk u&3 of the 64B row (BK=32 bf16).
  const int uA0 = t, uA1 = t + 256;              // A units 0..511
  const int uB0 = t, uB1 = t + 256;              // B units 0..511

  #define STAGE(ks, buf) do {                                                   \
    const int k0 = (ks) * 32;                                                   \
    unsigned short* as = &As[0][0] + (buf) * (128 * 32);                        \
    unsigned short* bs = &Bs[0][0] + (buf) * (128 * 32);                        \
    GLOAD16(Abase + (size_t)(uA0 >> 2) * K_DIM + k0 + (uA0 & 3) * 8, as + uA0 * 8); \
    GLOAD16(Abase + (size_t)(uA1 >> 2) * K_DIM + k0 + (uA1 & 3) * 8, as + uA1 * 8); \
    GLOAD16(Bbase + (size_t)(uB0 >> 2) * K_DIM + k0 + (uB0 & 3) * 8, bs + uB0 * 8); \
    GLOAD16(Bbase + (size_t)(uB1 >> 2) * K_DIM + k0 + (uB1 & 3) * 8, bs + uB1 * 8); \
  } while (0)

  #define COMPUTE(buf) do {                                                      \
    const unsigned short* as = &As[0][0] + (buf) * (128 * 32);                   \
    const unsigned short* bs = &Bs[0][0] + (buf) * (128 * 32);                   \
    bf16x8 af[4], bfv[4];                                                        \
    _Pragma("unroll")                                                            \
    for (int f = 0; f < 4; ++f) {                                                \
      af[f]  = *(const bf16x8*)(as + (wr * 64 + f * 16 + lr) * 32 + lg * 8);     \
      bfv[f] = *(const bf16x8*)(bs + (wc * 64 + f * 16 + lr) * 32 + lg * 8);     \
    }                                                                            \
    _Pragma("unroll")                                                            \
    for (int fr = 0; fr < 4; ++fr)                                               \
      _Pragma("unroll")                                                          \
      for (int fc = 0; fc < 4; ++fc)                                             \
        acc[fr][fc] = __builtin_amdgcn_mfma_f32_16x16x32_bf16(af[fr], bfv[fc],   \
                                                              acc[fr][fc], 0, 0, 0); \
  } while (0)

  STAGE(0, 0);
  STAGE(1, 1);
  int b_cur = 0;
  #pragma unroll 1
  for (int ks = 0; ks < NS; ++ks) {
    if (ks == NS - 1) {
      asm volatile("s_waitcnt vmcnt(0)" ::: "memory");
    } else {
      asm volatile("s_waitcnt vmcnt(4)" ::: "memory");   // stage ks landed
    }
    __builtin_amdgcn_sched_barrier(0);
    __builtin_amdgcn_s_barrier();
    if (ks + 2 < NS) {
      const int b_stg = (b_cur == 0) ? 2 : b_cur - 1;    // (ks+2)%3
      STAGE(ks + 2, b_stg);
    }
    COMPUTE(b_cur);
    b_cur = (b_cur == 2) ? 0 : b_cur + 1;
  }
  #undef STAGE
  #undef COMPUTE

  #pragma unroll
  for (int fr = 0; fr < 4; ++fr) {
    #pragma unroll
    for (int fc = 0; fc < 4; ++fc) {
      const int m0 = br * 128 + wr * 64 + fr * 16 + lg * 4;
      const int n  = bc * 128 + wc * 64 + fc * 16 + lr;
      if (MODE == 0) {
        const int which = n >> 10, rem = n & 1023;
        const int h = rem >> 6, d = rem & 63;
        const int b = m0 >> 11, tt0 = m0 & 2047;
        const int bh = b * NH + h;
        if (which == 2) {
          u16x4 pack;
          #pragma unroll
          for (int r = 0; r < 4; ++r) pack[r] = f2bf(acc[fr][fc][r] + bias[n]);
          *(u16x4*)(vTout + ((size_t)bh * HD + d) * T_SEQ + tt0) = pack;
        } else {
          unsigned short* o = (which == 0) ? qout : kout;
          const float sc = (which == 0) ? 0.18033688011112042f : 1.0f;  // 0.125*log2(e)
          #pragma unroll
          for (int r = 0; r < 4; ++r)
            o[((size_t)bh * T_SEQ + tt0 + r) * HD + d] = f2bf((acc[fr][fc][r] + bias[n]) * sc);
        }
      } else {
        #pragma unroll
        for (int r = 0; r < 4; ++r)
          fout[(size_t)(m0 + r) * 1024 + n] = acc[fr][fc][r] + bias[n];
      }
    }
  }
}

// ---- causal flash attention, v4 (unchanged from round 4) ----
__global__ __launch_bounds__(256, 4) void flash_attn_kernel(
    const unsigned short* __restrict__ qg,
    const unsigned short* __restrict__ kg,
    const unsigned short* __restrict__ vTg,
    unsigned short* __restrict__ yg) {
  __shared__ __align__(16) unsigned short Ks[2][64 * 64];
  __shared__ __align__(16) unsigned short Vs[2][64 * 64];

  const int t = threadIdx.x;
  const int w = t >> 6, l = t & 63;
  const int lr = l & 15, lg = l >> 4;
  const int i = blockIdx.x;
  const int bh = (i & 7) * 4 + ((i >> 3) & 3);   // 4 heads per XCD
  const int qt = 31 - (i >> 5);                  // longest blocks launch first
  const int nt = qt + 1;
  const int qw = qt * 64 + w * 16;
  const int qrow = qw + lr;
  const int swz = lr & 7;

  const int srow0 = t >> 3;
  const int sch = t & 7;

  const size_t kgb = (size_t)bh * T_SEQ * HD;
  const size_t vgb = (size_t)bh * HD * T_SEQ;
  const f32x4 zf = {0.f, 0.f, 0.f, 0.f};

  const size_t qoff = ((size_t)bh * T_SEQ + qw + lr) * HD + lg * 8;
  const bf16x8 qf0 = *(const bf16x8*)(qg + qoff);      // pre-scaled by 0.125*log2e
  const bf16x8 qf1 = *(const bf16x8*)(qg + qoff + 32);

  f32x4 acc[4];
  #pragma unroll
  for (int k = 0; k < 4; ++k) acc[k] = zf;
  float m_run = 0.f;
  float l_part = 0.f;

  #pragma unroll
  for (int sh = 0; sh < 2; ++sh) {
    const int row = sh * 32 + srow0;
    const int sc = (sch ^ (row & 7)) * 8;
    GLOAD16(kg + kgb + (size_t)row * HD + sc, Ks[0] + row * 64 + sch * 8);
    GLOAD16(vTg + vgb + (size_t)row * T_SEQ + sc, Vs[0] + row * 64 + sch * 8);
  }
  __syncthreads();

  int cur = 0;
  #pragma unroll 1
  for (int it = 0; it < nt; ++it) {
    const int kv0 = it * 64;
    if (it + 1 < nt) {
      const int kvn = kv0 + 64;
      #pragma unroll
      for (int sh = 0; sh < 2; ++sh) {
        const int row = sh * 32 + srow0;
        const int sc = (sch ^ (row & 7)) * 8;
        GLOAD16(kg + kgb + (size_t)(kvn + row) * HD + sc, Ks[cur ^ 1] + row * 64 + sch * 8);
        GLOAD16(vTg + vgb + (size_t)row * T_SEQ + kvn + sc, Vs[cur ^ 1] + row * 64 + sch * 8);
      }
    }

    f32x4 s[4];
    __builtin_amdgcn_s_setprio(1);
    #pragma unroll
    for (int fc = 0; fc < 4; ++fc) {
      const unsigned short* kr = Ks[cur] + (fc * 16 + lr) * 64;
      const bf16x8 k0v = *(const bf16x8*)(kr + ((lg ^ swz) * 8));
      const bf16x8 k1v = *(const bf16x8*)(kr + (((lg + 4) ^ swz) * 8));
      f32x4 sv = zf;
      sv = __builtin_amdgcn_mfma_f32_16x16x32_bf16(k0v, qf0, sv, 0, 0, 0);
      sv = __builtin_amdgcn_mfma_f32_16x16x32_bf16(k1v, qf1, sv, 0, 0, 0);
      s[fc] = sv;
    }
    __builtin_amdgcn_s_setprio(0);

    if (it == nt - 1) {           // causal mask: diagonal tile only
      #pragma unroll
      for (int fc = 0; fc < 4; ++fc)
        #pragma unroll
        for (int r = 0; r < 4; ++r) {
          const int tkv = kv0 + fc * 16 + lg * 4 + r;
          if (tkv > qrow) s[fc][r] = -1e30f;
        }
    }

    float mt = s[0][0];
    #pragma unroll
    for (int fc = 0; fc < 4; ++fc)
      #pragma unroll
      for (int r = 0; r < 4; ++r) mt = fmaxf(mt, s[fc][r]);
    if (__any(mt > m_run + 8.f)) {       // defer-max: rare path
      float mrow = fmaxf(mt, __shfl_xor(mt, 16));
      mrow = fmaxf(mrow, __shfl_xor(mrow, 32));
      const float m_new = fmaxf(m_run, mrow);
      const float fac = __builtin_amdgcn_exp2f(m_run - m_new);
      l_part *= fac;
      float frs[4];
      #pragma unroll
      for (int r = 0; r < 4; ++r) frs[r] = __shfl(fac, lg * 4 + r);
      #pragma unroll
      for (int fd = 0; fd < 4; ++fd)
        #pragma unroll
        for (int r = 0; r < 4; ++r) acc[fd][r] *= frs[r];
      m_run = m_new;
    }

    union { uint32_t d[2]; bf16x4 v; } pkd[4];
    #pragma unroll
    for (int fc = 0; fc < 4; ++fc) {
      float e0 = __builtin_amdgcn_exp2f(s[fc][0] - m_run);
      float e1 = __builtin_amdgcn_exp2f(s[fc][1] - m_run);
      float e2 = __builtin_amdgcn_exp2f(s[fc][2] - m_run);
      float e3 = __builtin_amdgcn_exp2f(s[fc][3] - m_run);
      l_part += (e0 + e1) + (e2 + e3);
      pkd[fc].d[0] = cvtpk_bf16(e0, e1);
      pkd[fc].d[1] = cvtpk_bf16(e2, e3);
    }

    __builtin_amdgcn_s_setprio(1);
    #pragma unroll
    for (int fd = 0; fd < 4; ++fd) {
      const unsigned short* vr = Vs[cur] + (fd * 16 + lr) * 64;
      bf16x4 vf[4];
      #pragma unroll
      for (int fc = 0; fc < 4; ++fc) {
        const int ch = (fc * 2 + (lg >> 1)) ^ swz;
        vf[fc] = *(const bf16x4*)(vr + ch * 8 + (lg & 1) * 4);
      }
      f32x4 a = acc[fd];
      #pragma unroll
      for (int fc = 0; fc < 4; ++fc) a = mfma16(pkd[fc].v, vf[fc], a);
      acc[fd] = a;
    }
    __builtin_amdgcn_s_setprio(0);
    __syncthreads();
    cur ^= 1;
  }

  float lsum = l_part;
  lsum += __shfl_xor(lsum, 16);
  lsum += __shfl_xor(lsum, 32);

  const int b = bh >> 4, h = bh & 15;
  #pragma unroll
  for (int r = 0; r < 4; ++r) {
    const float lv = __shfl(lsum, lg * 4 + r);
    const float linv = 1.f / lv;
    const int tt = qw + lg * 4 + r;
    #pragma unroll
    for (int fd = 0; fd < 4; ++fd) {
      const int d = fd * 16 + lr;
      yg[(((size_t)b * T_SEQ + tt) * NH + h) * HD + d] = f2bf(acc[fd][r] * linv);
    }
  }
}

extern "C" void kernel_launch(void* const* d_in, const int* in_sizes, int n_in,
                              void* d_out, int out_size, void* d_ws, size_t ws_size,
                              hipStream_t stream) {
  (void)in_sizes; (void)n_in; (void)out_size; (void)ws_size;
  const float* x      = (const float*)d_in[0];
  const float* w_attn = (const float*)d_in[1];
  const float* b_attn = (const float*)d_in[2];
  const float* w_proj = (const float*)d_in[3];
  const float* b_proj = (const float*)d_in[4];
  float* out = (float*)d_out;

  char* ws = (char*)d_ws;
  unsigned short* xb     = (unsigned short*)(ws);                  // 8 MiB  [4096][1024]
  unsigned short* wqkvT  = (unsigned short*)(ws + (8ull  << 20));  // 6 MiB  [3072][1024]
  unsigned short* wprojT = (unsigned short*)(ws + (14ull << 20));  // 2 MiB  [1024][1024]
  unsigned short* qb     = (unsigned short*)(ws + (16ull << 20));  // 8 MiB  [BH][T][D]
  unsigned short* kb     = (unsigned short*)(ws + (24ull << 20));  // 8 MiB  [BH][T][D]
  unsigned short* vT     = (unsigned short*)(ws + (32ull << 20));  // 8 MiB  [BH][D][T]
  unsigned short* yb     = (unsigned short*)(ws + (40ull << 20));  // 8 MiB  [4096][1024]

  prep_kernel<<<5120, 256, 0, stream>>>(x, xb, w_attn, wqkvT, w_proj, wprojT);
  gemm3_kernel<0><<<768, 256, 0, stream>>>(xb, wqkvT, b_attn, qb, kb, vT, nullptr);
  flash_attn_kernel<<<1024, 256, 0, stream>>>(qb, kb, vT, yb);
  gemm3_kernel<1><<<256, 256, 0, stream>>>(yb, wprojT, b_proj, nullptr, nullptr, nullptr, out);
}